// Round 7
// baseline (530.531 us; speedup 1.0000x reference)
//
#include <hip/hip_runtime.h>
#include <hip/hip_bf16.h>
#include <cstdint>

// Problem constants
#define DPROJ  8384

typedef __attribute__((ext_vector_type(8))) short short8;
typedef __attribute__((ext_vector_type(4))) short sh4;
typedef __attribute__((ext_vector_type(4))) float f32x4;

// workspace offsets (float units)
#define ZX_OFF     0ul
#define DTB_OFF    34340864ul   // [b][h][l] dt (softplus'd)
#define ACU_OFF    34603008ul   // [b][h][l] within-chunk cumsum of dt*A
#define CBT_OFF    34865152ul   // bf16 cbtT [b][c][l][s]  (C·B^T transposed)
#define ST_OFF     36175872ul   // [b][c][h][p][n] states -> prev_states
#define YB_OFF     40370176ul   // [b][h][l][p] ssd output
#define HALO_OFF   57147392ul   // [b][lc][3][ch] conv halo
// aliases (disjoint lifetimes):
#define U16_OFF    40370176ul   // bf16 u  (dead before ydiag writes yb)
#define WIN16_OFF  48758784ul   // bf16 W_in (dead before halo written)
#define WOUT16_OFF 34340864ul   // bf16 W_out (written after ydiag frees dtb)

__device__ __forceinline__ short f2bf(float x) {
  union { float f; uint32_t u; } v{x};
  uint32_t r = (v.u + 0x7fff + ((v.u >> 16) & 1)) >> 16;
  return (short)r;
}
__device__ __forceinline__ float bf2f(short s) {
  union { uint32_t u; float f; } v;
  v.u = ((uint32_t)(uint16_t)s) << 16;
  return v.f;
}

// ---------------- fp32 -> bf16 cast (8 elems/thread) -------------------------
__global__ __launch_bounds__(256) void cast_bf16_kernel(
    const float* __restrict__ in, short* __restrict__ out, int n8) {
  int i = blockIdx.x * 256 + threadIdx.x;
  if (i >= n8) return;
  const float4* p = (const float4*)(in + (size_t)i * 8);
  float4 a = p[0], b = p[1];
  short8 o;
  o[0] = f2bf(a.x); o[1] = f2bf(a.y); o[2] = f2bf(a.z); o[3] = f2bf(a.w);
  o[4] = f2bf(b.x); o[5] = f2bf(b.y); o[6] = f2bf(b.z); o[7] = f2bf(b.w);
  *(short8*)(out + (size_t)i * 8) = o;
}

__device__ __forceinline__ void gload16(const void* g, const void* l) {
  __builtin_amdgcn_global_load_lds(
      (const __attribute__((address_space(1))) void*)g,
      (__attribute__((address_space(3))) void*)l, 16, 0, 0);
}

// ============ 8-phase 256x256 bf16 GEMM (NT), BK=64, counted vmcnt ===========
// 512 threads / 8 waves (2 wm x 4 wn). LDS: 2 dbuf x 2 k-half planes [256][32]
// per operand = 128 KB. Per K-tile: 4 phases; stage one half-plane of tile t+1
// per phase into the dead buffer; vmcnt(4)+s_barrier every 2 phases (forces
// exactly the halves the next 2 phases read; 2 youngest halves stay in
// flight). T2 XOR-swizzle (k-chunk ^= row&3) on both write-source and read.
__global__ __launch_bounds__(512, 2) void gemm_8ph(
    const short* __restrict__ A, int lda, const short* __restrict__ B, int ldb,
    float* __restrict__ C, int ldc, int K, int Nvalid) {
  __shared__ __align__(16) short Al[2][2][8192];  // [dbuf][khalf][256*32]
  __shared__ __align__(16) short Bl[2][2][8192];
  const int t = threadIdx.x;
  const int w = t >> 6, lane = t & 63;
  const int wm = w >> 2, wn = w & 3;
  const int fr = lane & 15, fko = (lane >> 4) * 8;
  // XCD-chunked bijective tile swizzle (gridDim.y % 8 == 0)
  const int orig = blockIdx.x + gridDim.x * blockIdx.y;
  const int xcd = orig & 7, cid = orig >> 3, rpx = gridDim.y >> 3;
  const int tn = cid / rpx, tm = xcd * rpx + cid % rpx;
  const int m0 = tm * 256, n0 = tn * 256;
  // staging coords: call c in {0,1}; row r = c*128 + w*16 + (lane>>2);
  // source k-chunk pre-swizzled so linear LDS write + swizzled read match.
  const int sr = lane >> 2;          // 0..15
  const int sck = (lane & 3) * 8;    // short offset of 8-short chunk

  f32x4 acc[8][4];
#pragma unroll
  for (int i = 0; i < 8; ++i)
#pragma unroll
    for (int j = 0; j < 4; ++j) acc[i][j] = (f32x4){0.f, 0.f, 0.f, 0.f};

  const int nt = K >> 6;

#define STAGE_A(kt, hh, dd)                                                    \
  {                                                                            \
    _Pragma("unroll") for (int c = 0; c < 2; ++c) {                            \
      int r_ = c * 128 + w * 16 + sr;                                          \
      int ks_ = (kt)*64 + (hh)*32 + (sck ^ ((r_ & 3) << 3));                   \
      gload16(A + (size_t)(m0 + r_) * lda + ks_,                               \
              &Al[dd][hh][c * 4096 + w * 512 + lane * 8]);                     \
    }                                                                          \
  }
#define STAGE_B(kt, hh, dd)                                                    \
  {                                                                            \
    _Pragma("unroll") for (int c = 0; c < 2; ++c) {                            \
      int r_ = c * 128 + w * 16 + sr;                                          \
      int br_ = n0 + r_;                                                       \
      if (br_ > Nvalid - 1) br_ = Nvalid - 1;                                  \
      int ks_ = (kt)*64 + (hh)*32 + (sck ^ ((r_ & 3) << 3));                   \
      gload16(B + (size_t)br_ * ldb + ks_,                                     \
              &Bl[dd][hh][c * 4096 + w * 512 + lane * 8]);                     \
    }                                                                          \
  }
#define LOAD_BG(dd, hh, BG)                                                    \
  _Pragma("unroll") for (int j = 0; j < 4; ++j) {                              \
    int r_ = wn * 64 + j * 16 + fr;                                            \
    BG[j] = *(const short8*)&Bl[dd][hh][r_ * 32 + (fko ^ ((r_ & 3) << 3))];    \
  }
#define COMPUTE4(dd, hh, I0, BG)                                               \
  {                                                                            \
    short8 af_[4];                                                             \
    _Pragma("unroll") for (int ii = 0; ii < 4; ++ii) {                         \
      int r_ = wm * 128 + ((I0) + ii) * 16 + fr;                               \
      af_[ii] = *(const short8*)&Al[dd][hh][r_ * 32 + (fko ^ ((r_ & 3) << 3))];\
    }                                                                          \
    __builtin_amdgcn_s_setprio(1);                                             \
    _Pragma("unroll") for (int ii = 0; ii < 4; ++ii)                           \
        _Pragma("unroll") for (int j = 0; j < 4; ++j)                          \
            acc[(I0) + ii][j] = __builtin_amdgcn_mfma_f32_16x16x32_bf16(       \
                af_[ii], BG[j], acc[(I0) + ii][j], 0, 0, 0);                   \
    __builtin_amdgcn_s_setprio(0);                                             \
  }

  // prologue: stage tile 0 fully into dbuf 0; force k0 halves (k1 may fly)
  STAGE_A(0, 0, 0);
  STAGE_B(0, 0, 0);
  STAGE_A(0, 1, 0);
  STAGE_B(0, 1, 0);
  asm volatile("s_waitcnt vmcnt(4)" ::: "memory");
  __builtin_amdgcn_s_barrier();

  int d = 0;
  for (int kt = 0; kt < nt; ++kt, d ^= 1) {
    const int nk = (kt + 1 < nt) ? kt + 1 : 0;  // wrap: harmless re-stage
    // ---- k-half 0 ----
    STAGE_A(nk, 0, d ^ 1);
    {
      short8 bg[4];
      LOAD_BG(d, 0, bg);
      COMPUTE4(d, 0, 0, bg);
      STAGE_B(nk, 0, d ^ 1);
      COMPUTE4(d, 0, 4, bg);
    }
    asm volatile("s_waitcnt vmcnt(4)" ::: "memory");  // forces tile kt k1
    __builtin_amdgcn_s_barrier();
    // ---- k-half 1 ----
    STAGE_A(nk, 1, d ^ 1);
    {
      short8 bg[4];
      LOAD_BG(d, 1, bg);
      COMPUTE4(d, 1, 0, bg);
      STAGE_B(nk, 1, d ^ 1);
      COMPUTE4(d, 1, 4, bg);
    }
    asm volatile("s_waitcnt vmcnt(4)" ::: "memory");  // forces tile kt+1 k0
    __builtin_amdgcn_s_barrier();
  }
#undef STAGE_A
#undef STAGE_B
#undef LOAD_BG
#undef COMPUTE4

  // epilogue: store
#pragma unroll
  for (int i = 0; i < 8; ++i) {
    const int row = m0 + wm * 128 + i * 16 + (lane >> 4) * 4;
#pragma unroll
    for (int j = 0; j < 4; ++j) {
      const int col = n0 + wn * 64 + j * 16 + fr;
      if (col < Nvalid) {
#pragma unroll
        for (int r = 0; r < 4; ++r)
          C[(size_t)(row + r) * ldc + col] = acc[i][j][r];
      }
    }
  }
}

// ---------------- m97-style bf16 GEMM (kept for out_proj) --------------------
__global__ __launch_bounds__(256) void gemm_bf16(
    const short* __restrict__ A, int lda, const short* __restrict__ B, int ldb,
    float* __restrict__ C, int ldc, int K, int Nvalid) {
  const int orig = blockIdx.x + gridDim.x * blockIdx.y;
  const int xcd = orig & 7;
  const int cid = orig >> 3;
  const int rpx = gridDim.y >> 3;  // rows per XCD
  const int tn = cid / rpx;
  const int tm = xcd * rpx + (cid % rpx);
  __shared__ __align__(16) short As[128 * 32];
  __shared__ __align__(16) short Bs[128 * 32];
  const int t = threadIdx.x;
  const int w = t >> 6, lane = t & 63;
  const int m0 = tm * 128, n0 = tn * 128;
  const int wr = (w >> 1) * 64, wc = (w & 1) * 64;
  const int arow = t >> 2, kk = (t & 3) * 8;
  const int fr = lane & 15, fk = (lane >> 4) * 8;
  int br0 = n0 + arow;       if (br0 > Nvalid - 1) br0 = Nvalid - 1;
  int br1 = n0 + 64 + arow;  if (br1 > Nvalid - 1) br1 = Nvalid - 1;
  const short* pa0 = A + (size_t)(m0 + arow) * lda + kk;
  const short* pa1 = A + (size_t)(m0 + 64 + arow) * lda + kk;
  const short* pb0 = B + (size_t)br0 * ldb + kk;
  const short* pb1 = B + (size_t)br1 * ldb + kk;
  short* la = As + w * 512;
  short* lb = Bs + w * 512;
  f32x4 acc[4][4];
#pragma unroll
  for (int i = 0; i < 4; ++i)
#pragma unroll
    for (int j = 0; j < 4; ++j) acc[i][j] = (f32x4){0.f, 0.f, 0.f, 0.f};

  for (int k0 = 0; k0 < K; k0 += 32) {
    gload16(pa0 + k0, la);
    gload16(pa1 + k0, la + 2048);
    gload16(pb0 + k0, lb);
    gload16(pb1 + k0, lb + 2048);
    __syncthreads();
    short8 af[4], bg[4];
#pragma unroll
    for (int i = 0; i < 4; ++i) {
      af[i] = *(const short8*)&As[(wr + i * 16 + fr) * 32 + fk];
      bg[i] = *(const short8*)&Bs[(wc + i * 16 + fr) * 32 + fk];
    }
#pragma unroll
    for (int i = 0; i < 4; ++i)
#pragma unroll
      for (int j = 0; j < 4; ++j)
        acc[i][j] = __builtin_amdgcn_mfma_f32_16x16x32_bf16(af[i], bg[j],
                                                            acc[i][j], 0, 0, 0);
    __syncthreads();
  }
#pragma unroll
  for (int i = 0; i < 4; ++i) {
    const int row = m0 + wr + i * 16 + (lane >> 4) * 4;
#pragma unroll
    for (int j = 0; j < 4; ++j) {
      const int col = n0 + wc + j * 16 + fr;
      if (col < Nvalid) {
#pragma unroll
        for (int r = 0; r < 4; ++r)
          C[(size_t)(row + r) * ldc + col] = acc[i][j][r];
      }
    }
  }
}

// ---------------- conv halo save (before in-place conv) ----------------------
__global__ __launch_bounds__(256) void halo_kernel(const float* __restrict__ zx,
                                                   float* __restrict__ halo) {
  int idx = blockIdx.x * 256 + threadIdx.x;
  int ch = idx % 4224;
  int r = idx / 4224;
  int j = r % 3;
  int r2 = r / 3;
  int lc = r2 & 15, b = r2 >> 4;
  int l = lc * 128 - 3 + j;
  halo[idx] = (l < 0) ? 0.f : zx[(size_t)(b * 2048 + l) * DPROJ + 4096 + ch];
}

// ---------------- causal conv1d(4) + silu, in place on xBC slice -------------
__global__ __launch_bounds__(256) void conv_kernel(float* __restrict__ zx,
                                                   const float* __restrict__ halo,
                                                   const float* __restrict__ cw,
                                                   const float* __restrict__ cb) {
  int idx = blockIdx.x * 256 + threadIdx.x;
  int ch = idx % 4224;
  int r = idx / 4224;
  int lc = r & 15, b = r >> 4;
  float w0 = cw[ch * 4 + 0], w1 = cw[ch * 4 + 1], w2 = cw[ch * 4 + 2],
        w3 = cw[ch * 4 + 3];
  float bias = cb[ch];
  const float* hp = halo + (size_t)r * 3 * 4224 + ch;
  float x3 = hp[0], x2 = hp[4224], x1 = hp[2 * 4224];
  size_t base = (size_t)(b * 2048 + lc * 128) * DPROJ + 4096 + ch;
  for (int i = 0; i < 128; ++i) {
    float x0 = zx[base];
    float v = bias + w0 * x3 + w1 * x2 + w2 * x1 + w3 * x0;
    v = v / (1.f + __expf(-v));
    zx[base] = v;
    x3 = x2; x2 = x1; x1 = x0;
    base += DPROJ;
  }
}

// ---------------- dt softplus + per-chunk cumsum of dt*A ---------------------
__global__ __launch_bounds__(256) void dtacum_kernel(
    const float* __restrict__ zx, const float* __restrict__ dt_bias,
    const float* __restrict__ A_log, float* __restrict__ dtb,
    float* __restrict__ acu) {
  int bid = blockIdx.x;
  int c = bid & 7, h = (bid >> 3) & 63, b = bid >> 9;
  int s = threadIdx.x;
  int tok = b * 2048 + c * 256 + s;
  float raw = zx[(size_t)tok * DPROJ + 8320 + h] + dt_bias[h];
  float dtv = (raw > 20.f) ? raw : log1pf(expf(raw));
  float A = -expf(A_log[h]);
  __shared__ float sc[256];
  sc[s] = dtv * A;
  __syncthreads();
  for (int off = 1; off < 256; off <<= 1) {
    float v = (s >= off) ? sc[s - off] : 0.f;
    __syncthreads();
    sc[s] += v;
    __syncthreads();
  }
  int o = (b * 64 + h) * 2048 + c * 256 + s;
  dtb[o] = dtv;
  acu[o] = sc[s];
}

// ---------------- CB^T per (b,c), TRANSPOSED bf16: cbtT[l][s] ----------------
__global__ __launch_bounds__(256) void cbt_kernel(const float* __restrict__ zx,
                                                  short* __restrict__ cbtT) {
  __shared__ float cl[256][33];
  __shared__ float blds[16][32];
  int bid = blockIdx.x;
  int sb = bid & 15, c = (bid >> 4) & 7, b = bid >> 7;
  int t = threadIdx.x;  // = l
  int tok0 = b * 2048 + c * 256;
  float acc[16];
#pragma unroll
  for (int i = 0; i < 16; ++i) acc[i] = 0.f;
  for (int nh = 0; nh < 2; ++nh) {
    __syncthreads();
    for (int it = 0; it < 32; ++it) {
      int e = it * 256 + t;
      int row = e >> 5, n = e & 31;
      cl[row][n] = zx[(size_t)(tok0 + row) * DPROJ + 8256 + nh * 32 + n];
    }
    for (int it = 0; it < 2; ++it) {
      int e = it * 256 + t;
      int row = e >> 5, n = e & 31;
      blds[row][n] =
          zx[(size_t)(tok0 + sb * 16 + row) * DPROJ + 8192 + nh * 32 + n];
    }
    __syncthreads();
    for (int n = 0; n < 32; ++n) {
      float cv = cl[t][n];
#pragma unroll
      for (int s2 = 0; s2 < 16; ++s2) acc[s2] += cv * blds[s2][n];
    }
  }
  short* outp = cbtT + ((size_t)(b * 8 + c) * 256 + t) * 256 + sb * 16;
#pragma unroll
  for (int s2 = 0; s2 < 16; ++s2) outp[s2] = f2bf(acc[s2]);
}

// ---------------- states (MFMA): st[p][n] = sum_s x[s,p] B[s,n] w[s] ---------
__global__ __launch_bounds__(256) void states_mfma(
    const float* __restrict__ zx, const float* __restrict__ dtb,
    const float* __restrict__ acu, float* __restrict__ st) {
  __shared__ __align__(16) short As2[64][136];  // X^T [p][k]
  __shared__ __align__(16) short Bs2[64][136];  // (B·w)^T [n][k]
  __shared__ float wl[256];
  int bid = blockIdx.x;  // (b*8+c)*64 + h
  int h = bid & 63, c = (bid >> 6) & 7, b = bid >> 9;
  int t = threadIdx.x;
  int w = t >> 6, lane = t & 63;
  int tok0 = b * 2048 + c * 256;
  int bh = (b * 64 + h) * 2048 + c * 256;
  {
    float aend = acu[bh + 255];
    wl[t] = __expf(aend - acu[bh + t]) * dtb[bh + t];
  }
  __syncthreads();
  const float* xbase = zx + (size_t)tok0 * DPROJ + 4096 + h * 64;
  const float* bbase = zx + (size_t)tok0 * DPROJ + 8192;
  const int fr = lane & 15, fko = (lane >> 4) * 8;
  const int wi = (w >> 1) * 32, wj = (w & 1) * 32;
  f32x4 acc[2][2];
#pragma unroll
  for (int i = 0; i < 2; ++i)
#pragma unroll
    for (int j = 0; j < 2; ++j) acc[i][j] = (f32x4){0.f, 0.f, 0.f, 0.f};

  for (int ph = 0; ph < 2; ++ph) {
    const int kb = ph * 128;
    if (ph) __syncthreads();
    for (int it = 0; it < 8; ++it) {
      int idx = it * 256 + t;
      int p = idx & 63, kg = idx >> 6;  // kg 0..31
      int k = kb + kg * 4;
      const float* xp = xbase + (size_t)k * DPROJ + p;
      const float* bp = bbase + (size_t)k * DPROJ + p;
      sh4 oa, ob;
#pragma unroll
      for (int r = 0; r < 4; ++r) {
        oa[r] = f2bf(xp[(size_t)r * DPROJ]);
        ob[r] = f2bf(bp[(size_t)r * DPROJ] * wl[k + r]);
      }
      *(sh4*)&As2[p][kg * 4] = oa;
      *(sh4*)&Bs2[p][kg * 4] = ob;
    }
    __syncthreads();
#pragma unroll
    for (int kk0 = 0; kk0 < 128; kk0 += 32) {
      short8 af[2], bg[2];
#pragma unroll
      for (int i = 0; i < 2; ++i) {
        af[i] = *(const short8*)&As2[wi + i * 16 + fr][kk0 + fko];
        bg[i] = *(const short8*)&Bs2[wj + i * 16 + fr][kk0 + fko];
      }
#pragma unroll
      for (int i = 0; i < 2; ++i)
#pragma unroll
        for (int j = 0; j < 2; ++j)
          acc[i][j] = __builtin_amdgcn_mfma_f32_16x16x32_bf16(af[i], bg[j],
                                                              acc[i][j], 0, 0, 0);
    }
  }
  float* out = st + ((size_t)(b * 8 + c) * 64 + h) * 4096;
  const int rq = (lane >> 4) * 4;
#pragma unroll
  for (int i = 0; i < 2; ++i) {
    int p0 = wi + i * 16 + rq;
#pragma unroll
    for (int j = 0; j < 2; ++j) {
      int n = wj + j * 16 + fr;
#pragma unroll
      for (int r = 0; r < 4; ++r)
        out[(size_t)(p0 + r) * 64 + n] = acc[i][j][r];
    }
  }
}

// ---------------- inter-chunk scan (in place states -> prev_states) ---------
__global__ __launch_bounds__(256) void chunkscan_kernel(
    const float* __restrict__ acu, float* __restrict__ st) {
  int bid = blockIdx.x;
  int pc = bid & 15, h = (bid >> 4) & 63, b = bid >> 10;
  int pn = pc * 256 + threadIdx.x;
  int abase = (b * 64 + h) * 2048;
  float run = 0.f;
  for (int c = 0; c < 8; ++c) {
    size_t idx = ((size_t)(b * 8 + c) * 64 + h) * 4096 + pn;
    float s = st[idx];
    st[idx] = run;
    float ach = acu[abase + c * 256 + 255];
    run = run * __expf(ach) + s;
  }
}

// ---------------- Y (MFMA): M=256 l, N=64 p, K=320 (256 s + 64 n) ------------
__global__ __launch_bounds__(256) void ydiag_mfma(
    const float* __restrict__ zx, const float* __restrict__ dtb,
    const float* __restrict__ acu, const short* __restrict__ cbtT,
    const float* __restrict__ st, const float* __restrict__ Dp,
    float* __restrict__ yb) {
  __shared__ __align__(16) short Xs[64][328];  // [p][k]: k<256 x, k>=256 prev
  __shared__ float acs[256];
  __shared__ float dts[256];
  int bid = blockIdx.x;  // (b*8+c)*64 + h
  int h = bid & 63, c = (bid >> 6) & 7, b = bid >> 9;
  int t = threadIdx.x;
  int w = t >> 6, lane = t & 63;
  int tok0 = b * 2048 + c * 256;
  int bh = (b * 64 + h) * 2048 + c * 256;
  acs[t] = acu[bh + t];
  dts[t] = dtb[bh + t];
  const float* xbase = zx + (size_t)tok0 * DPROJ + 4096 + h * 64;
  const float* st_b = st + ((size_t)(b * 8 + c) * 64 + h) * 4096;
  for (int it = 0; it < 16; ++it) {
    int idx = it * 256 + t;
    int p = idx & 63, kg = idx >> 6;  // kg 0..63
    const float* xp = xbase + (size_t)(kg * 4) * DPROJ + p;
    sh4 o;
    o[0] = f2bf(xp[0]);
    o[1] = f2bf(xp[DPROJ]);
    o[2] = f2bf(xp[2 * DPROJ]);
    o[3] = f2bf(xp[3 * DPROJ]);
    *(sh4*)&Xs[p][kg * 4] = o;
  }
  for (int it = 0; it < 4; ++it) {
    int idx = it * 256 + t;
    int ng = idx & 15, p = idx >> 4;
    float4 v = *(const float4*)&st_b[p * 64 + ng * 4];
    sh4 o;
    o[0] = f2bf(v.x); o[1] = f2bf(v.y); o[2] = f2bf(v.z); o[3] = f2bf(v.w);
    *(sh4*)&Xs[p][256 + ng * 4] = o;
  }
  __syncthreads();

  const int fr = lane & 15, fko = (lane >> 4) * 8;
  const int wr = w * 64;
  float Al[4], eAl[4];
#pragma unroll
  for (int i = 0; i < 4; ++i) {
    Al[i] = acs[wr + i * 16 + fr];
    eAl[i] = __expf(Al[i]);
  }
  f32x4 acc[4][4];
#pragma unroll
  for (int i = 0; i < 4; ++i)
#pragma unroll
    for (int j = 0; j < 4; ++j) acc[i][j] = (f32x4){0.f, 0.f, 0.f, 0.f};

  const short* cbt_b = cbtT + (size_t)(b * 8 + c) * 65536;

  // masked decay part: s in [0, wr+64)
  for (int k0 = 0; k0 < wr + 64; k0 += 32) {
    short8 bg[4];
#pragma unroll
    for (int j = 0; j < 4; ++j)
      bg[j] = *(const short8*)&Xs[j * 16 + fr][k0 + fko];
    const int bi = (k0 + 32 < 256) ? (k0 + 32) : 255;
    const float base = acs[bi];
    float vd[8];
#pragma unroll
    for (int jj = 0; jj < 8; ++jj) {
      int s = k0 + fko + jj;
      vd[jj] = __expf(base - acs[s]) * dts[s];
    }
#pragma unroll
    for (int i = 0; i < 4; ++i) {
      const int li0 = wr + i * 16;
      if (k0 > li0 + 15) continue;  // fragment fully above diagonal: zero
      const int l = li0 + fr;
      const short8 cb = *(const short8*)&cbt_b[(size_t)l * 256 + k0 + fko];
      short8 af;
      if (k0 + 32 <= li0) {
        const float u = __expf(Al[i] - base);
#pragma unroll
        for (int jj = 0; jj < 8; ++jj)
          af[jj] = f2bf(bf2f(cb[jj]) * (vd[jj] * u));
      } else {
#pragma unroll
        for (int jj = 0; jj < 8; ++jj) {
          int s = k0 + fko + jj;
          float wv = 0.f;
          if (s <= l) wv = bf2f(cb[jj]) * __expf(Al[i] - acs[s]) * dts[s];
          af[jj] = f2bf(wv);
        }
      }
#pragma unroll
      for (int j = 0; j < 4; ++j)
        acc[i][j] = __builtin_amdgcn_mfma_f32_16x16x32_bf16(af, bg[j],
                                                            acc[i][j], 0, 0, 0);
    }
  }
  // Y_off part: k in [256, 320) -> n = k-256; C read straight from zx
#pragma unroll
  for (int k0 = 256; k0 < 320; k0 += 32) {
    short8 bg[4];
#pragma unroll
    for (int j = 0; j < 4; ++j)
      bg[j] = *(const short8*)&Xs[j * 16 + fr][k0 + fko];
#pragma unroll
    for (int i = 0; i < 4; ++i) {
      const int l = wr + i * 16 + fr;
      const float* cr =
          zx + (size_t)(tok0 + l) * DPROJ + 8256 + (k0 - 256) + fko;
      float4 c0 = *(const float4*)cr;
      float4 c1 = *(const float4*)(cr + 4);
      short8 af;
      af[0] = f2bf(c0.x * eAl[i]); af[1] = f2bf(c0.y * eAl[i]);
      af[2] = f2bf(c0.z * eAl[i]); af[3] = f2bf(c0.w * eAl[i]);
      af[4] = f2bf(c1.x * eAl[i]); af[5] = f2bf(c1.y * eAl[i]);
      af[6] = f2bf(c1.z * eAl[i]); af[7] = f2bf(c1.w * eAl[i]);
#pragma unroll
      for (int j = 0; j < 4; ++j)
        acc[i][j] = __builtin_amdgcn_mfma_f32_16x16x32_bf16(af, bg[j],
                                                            acc[i][j], 0, 0, 0);
    }
  }
  // epilogue: + D*x, store
  float Dh = Dp[h];
  const int rq = (lane >> 4) * 4;
#pragma unroll
  for (int i = 0; i < 4; ++i) {
    int l0 = wr + i * 16 + rq;
#pragma unroll
    for (int j = 0; j < 4; ++j) {
      int p = j * 16 + fr;
      sh4 x4 = *(const sh4*)&Xs[p][l0];
      f32x4 a = acc[i][j];
#pragma unroll
      for (int r = 0; r < 4; ++r)
        yb[(size_t)(bh + l0 + r) * 64 + p] = a[r] + Dh * bf2f(x4[r]);
    }
  }
}

// ---------------- gate + RMSNorm -> bf16 activations (aliases zx z-slice) ----
__global__ __launch_bounds__(256) void gatenorm_kernel(
    const float* zx, const float* __restrict__ nw,
    const float* __restrict__ yb, short* ybh) {
  int tok = blockIdx.x;
  int b = tok >> 11, l = tok & 2047;
  int t = threadIdx.x;
  float g[16];
  float ss = 0.f;
#pragma unroll
  for (int i = 0; i < 16; ++i) {
    int d = i * 256 + t;
    int h = d >> 6, p = d & 63;
    float yv = yb[((size_t)(b * 64 + h) * 2048 + l) * 64 + p];
    float zv = zx[(size_t)tok * DPROJ + d];
    float gv = yv * (zv / (1.f + __expf(-zv)));
    g[i] = gv;
    ss += gv * gv;
  }
  for (int off = 32; off > 0; off >>= 1) ss += __shfl_down(ss, off);
  __shared__ float red[4];
  int wid = t >> 6, lane = t & 63;
  if (lane == 0) red[wid] = ss;
  __syncthreads();
  float tot = red[0] + red[1] + red[2] + red[3];
  float scale = rsqrtf(tot * (1.f / 4096.f) + 1e-5f);
#pragma unroll
  for (int i = 0; i < 16; ++i) {
    int d = i * 256 + t;
    ybh[(size_t)tok * 16768 + d] = f2bf(g[i] * scale * nw[d]);
  }
}

extern "C" void kernel_launch(void* const* d_in, const int* in_sizes, int n_in,
                              void* d_out, int out_size, void* d_ws,
                              size_t ws_size, hipStream_t stream) {
  const float* u = (const float*)d_in[0];
  const float* W_in = (const float*)d_in[1];
  const float* conv_w = (const float*)d_in[2];
  const float* conv_b = (const float*)d_in[3];
  const float* dt_bias = (const float*)d_in[4];
  const float* A_log = (const float*)d_in[5];
  const float* Dp = (const float*)d_in[6];
  const float* norm_w = (const float*)d_in[7];
  const float* W_out = (const float*)d_in[8];
  float* out = (float*)d_out;
  float* ws = (float*)d_ws;

  float* zx = ws + ZX_OFF;
  float* dtb = ws + DTB_OFF;
  float* acu = ws + ACU_OFF;
  short* cbtT = (short*)(ws + CBT_OFF);
  float* st = ws + ST_OFF;
  float* yb = ws + YB_OFF;
  float* halo = ws + HALO_OFF;
  short* u16 = (short*)(ws + U16_OFF);
  short* win16 = (short*)(ws + WIN16_OFF);
  short* wout16 = (short*)(ws + WOUT16_OFF);
  short* ybh = (short*)zx;

  // 0. casts for in_proj
  cast_bf16_kernel<<<4096, 256, 0, stream>>>(u, u16, 1048576);
  cast_bf16_kernel<<<8384, 256, 0, stream>>>(W_in, win16, 2146304);
  // 1. in_proj (8-phase 256^2 MFMA): zx = u @ W_in^T (dt columns fused)
  gemm_8ph<<<dim3(33, 16), 512, 0, stream>>>(u16, 2048, win16, 2048, zx, DPROJ,
                                             2048, DPROJ);
  // 2. conv halo, in-place conv+silu
  halo_kernel<<<1584, 256, 0, stream>>>(zx, halo);
  conv_kernel<<<528, 256, 0, stream>>>(zx, halo, conv_w, conv_b);
  // 3. dt softplus + per-chunk cumsum (reads zx dt slice)
  dtacum_kernel<<<1024, 256, 0, stream>>>(zx, dt_bias, A_log, dtb, acu);
  // 4. shared C·B^T (transposed bf16)
  cbt_kernel<<<256, 256, 0, stream>>>(zx, cbtT);
  // 5. chunk states (MFMA) + inter-chunk scan
  states_mfma<<<1024, 256, 0, stream>>>(zx, dtb, acu, st);
  chunkscan_kernel<<<2048, 256, 0, stream>>>(acu, st);
  // 6. Y (MFMA)
  ydiag_mfma<<<1024, 256, 0, stream>>>(zx, dtb, acu, cbtT, st, Dp, yb);
  // 7. W_out cast
  cast_bf16_kernel<<<4096, 256, 0, stream>>>(W_out, wout16, 1048576);
  // 8. gate + RMSNorm -> bf16
  gatenorm_kernel<<<4096, 256, 0, stream>>>(zx, norm_w, yb, ybh);
  // 9. out_proj (bf16 MFMA, m97 structure)
  gemm_bf16<<<dim3(16, 32), 256, 0, stream>>>(ybh, 16768, wout16, 4096, out,
                                              2048, 4096, 2048);
}

// Round 8
// 514.349 us; speedup vs baseline: 1.0315x; 1.0315x over previous
//
#include <hip/hip_runtime.h>
#include <hip/hip_bf16.h>
#include <cstdint>

// Problem constants
#define DPROJ  8384

typedef __attribute__((ext_vector_type(8))) short short8;
typedef __attribute__((ext_vector_type(4))) short sh4;
typedef __attribute__((ext_vector_type(4))) float f32x4;

// workspace offsets (float units)
#define ZX_OFF     0ul
#define DTB_OFF    34340864ul   // [b][h][l] dt (softplus'd)
#define ACU_OFF    34603008ul   // [b][h][l] within-chunk cumsum of dt*A
#define CBT_OFF    34865152ul   // bf16 cbtT [b][c][l][s]  (C·B^T transposed)
#define ST_OFF     36175872ul   // [b][c][h][p][n] states -> prev_states
#define YB_OFF     40370176ul   // [b][h][l][p] ssd output
#define HALO_OFF   57147392ul   // [b][lc][3][ch] conv halo
// aliases (disjoint lifetimes):
#define U16_OFF    40370176ul   // bf16 u  (dead before ydiag writes yb)
#define WIN16_OFF  48758784ul   // bf16 W_in (dead before halo written)
#define WOUT16_OFF 34340864ul   // bf16 W_out (written after ydiag frees dtb)

__device__ __forceinline__ short f2bf(float x) {
  union { float f; uint32_t u; } v{x};
  uint32_t r = (v.u + 0x7fff + ((v.u >> 16) & 1)) >> 16;
  return (short)r;
}
__device__ __forceinline__ float bf2f(short s) {
  union { uint32_t u; float f; } v;
  v.u = ((uint32_t)(uint16_t)s) << 16;
  return v.f;
}

// ---------------- fp32 -> bf16 cast (8 elems/thread) -------------------------
__global__ __launch_bounds__(256) void cast_bf16_kernel(
    const float* __restrict__ in, short* __restrict__ out, int n8) {
  int i = blockIdx.x * 256 + threadIdx.x;
  if (i >= n8) return;
  const float4* p = (const float4*)(in + (size_t)i * 8);
  float4 a = p[0], b = p[1];
  short8 o;
  o[0] = f2bf(a.x); o[1] = f2bf(a.y); o[2] = f2bf(a.z); o[3] = f2bf(a.w);
  o[4] = f2bf(b.x); o[5] = f2bf(b.y); o[6] = f2bf(b.z); o[7] = f2bf(b.w);
  *(short8*)(out + (size_t)i * 8) = o;
}

__device__ __forceinline__ void gload16(const void* g, const void* l) {
  __builtin_amdgcn_global_load_lds(
      (const __attribute__((address_space(1))) void*)g,
      (__attribute__((address_space(3))) void*)l, 16, 0, 0);
}

// ============ 256x256 bf16 GEMM (NT), BK=64, full-tile prefetch ==============
// 512 threads / 8 waves (2 wm x 4 wn). LDS: 2 dbuf x [256][64] per operand =
// 128 KB. Per K-tile: issue ALL 8 next-tile loads, then vmcnt(8) (forces the
// current tile's 8, leaves next tile's in flight across the whole compute),
// barrier, 64 MFMA/wave, barrier. Prefetch window = full tile compute.
// T2 swizzle: 16B-chunk ^= (row>>1)&3 on source k and on ds_read (2-way free).
__global__ __launch_bounds__(512, 2) void gemm_8ph(
    const short* __restrict__ A, int lda, const short* __restrict__ B, int ldb,
    float* __restrict__ C, int ldc, int K, int Nvalid) {
  __shared__ __align__(16) short Al[2][16384];  // [dbuf][half*8192 + r*32 + k]
  __shared__ __align__(16) short Bl[2][16384];
  const int t = threadIdx.x;
  const int w = t >> 6, lane = t & 63;
  const int wm = w >> 2, wn = w & 3;
  const int fr = lane & 15, fko = (lane >> 4) * 8;
  // XCD-chunked bijective tile swizzle (gridDim.y % 8 == 0)
  const int orig = blockIdx.x + gridDim.x * blockIdx.y;
  const int xcd = orig & 7, cid = orig >> 3, rpx = gridDim.y >> 3;
  const int tn = cid / rpx, tm = xcd * rpx + cid % rpx;
  const int m0 = tm * 256, n0 = tn * 256;
  const int sr = lane >> 2;        // staging row within 16
  const int sck = (lane & 3) * 8;  // staging chunk (shorts)

  f32x4 acc[8][4];
#pragma unroll
  for (int i = 0; i < 8; ++i)
#pragma unroll
    for (int j = 0; j < 4; ++j) acc[i][j] = (f32x4){0.f, 0.f, 0.f, 0.f};

  const int nt = K >> 6;

#define SWZ(r_) ((((r_) >> 1) & 3) << 3)
#define STAGE_TILE(kt, dd)                                                     \
  {                                                                            \
    _Pragma("unroll") for (int hh = 0; hh < 2; ++hh)                           \
        _Pragma("unroll") for (int c = 0; c < 2; ++c) {                        \
      int r_ = c * 128 + w * 16 + sr;                                          \
      int ks_ = (kt)*64 + hh * 32 + (sck ^ SWZ(r_));                           \
      int br_ = n0 + r_;                                                       \
      if (br_ > Nvalid - 1) br_ = Nvalid - 1;                                  \
      int dst_ = hh * 8192 + c * 4096 + w * 512 + lane * 8;                    \
      gload16(A + (size_t)(m0 + r_) * lda + ks_, &Al[dd][dst_]);               \
      gload16(B + (size_t)br_ * ldb + ks_, &Bl[dd][dst_]);                     \
    }                                                                          \
  }
#define COMPUTE_HALF(dd, hh)                                                   \
  {                                                                            \
    short8 bg_[4];                                                             \
    _Pragma("unroll") for (int j = 0; j < 4; ++j) {                            \
      int r_ = wn * 64 + j * 16 + fr;                                          \
      bg_[j] = *(const short8*)&Bl[dd][hh * 8192 + r_ * 32 + (fko ^ SWZ(r_))]; \
    }                                                                          \
    _Pragma("unroll") for (int io = 0; io < 2; ++io) {                         \
      short8 af_[4];                                                           \
      _Pragma("unroll") for (int ii = 0; ii < 4; ++ii) {                       \
        int r_ = wm * 128 + (io * 4 + ii) * 16 + fr;                           \
        af_[ii] =                                                              \
            *(const short8*)&Al[dd][hh * 8192 + r_ * 32 + (fko ^ SWZ(r_))];    \
      }                                                                        \
      __builtin_amdgcn_s_setprio(1);                                           \
      _Pragma("unroll") for (int ii = 0; ii < 4; ++ii)                         \
          _Pragma("unroll") for (int j = 0; j < 4; ++j)                        \
              acc[io * 4 + ii][j] = __builtin_amdgcn_mfma_f32_16x16x32_bf16(   \
                  af_[ii], bg_[j], acc[io * 4 + ii][j], 0, 0, 0);              \
      __builtin_amdgcn_s_setprio(0);                                           \
    }                                                                          \
  }

  // prologue: stage tile 0 into dbuf 0
  STAGE_TILE(0, 0);
  int d = 0;
  for (int kt = 0; kt < nt; ++kt, d ^= 1) {
    const int nk = (kt + 1 < nt) ? kt + 1 : 0;  // wrap: staged, never read
    STAGE_TILE(nk, d ^ 1);                      // 8 loads in flight over compute
    asm volatile("s_waitcnt vmcnt(8)" ::: "memory");  // forces tile kt only
    __builtin_amdgcn_s_barrier();
    COMPUTE_HALF(d, 0);
    COMPUTE_HALF(d, 1);
    __builtin_amdgcn_s_barrier();  // all reads of buf d done before re-stage
  }
#undef SWZ
#undef STAGE_TILE
#undef COMPUTE_HALF

  // epilogue: store
#pragma unroll
  for (int i = 0; i < 8; ++i) {
    const int row = m0 + wm * 128 + i * 16 + (lane >> 4) * 4;
#pragma unroll
    for (int j = 0; j < 4; ++j) {
      const int col = n0 + wn * 64 + j * 16 + fr;
      if (col < Nvalid) {
#pragma unroll
        for (int r = 0; r < 4; ++r)
          C[(size_t)(row + r) * ldc + col] = acc[i][j][r];
      }
    }
  }
}

// ---------------- m97-style bf16 GEMM (kept for out_proj) --------------------
__global__ __launch_bounds__(256) void gemm_bf16(
    const short* __restrict__ A, int lda, const short* __restrict__ B, int ldb,
    float* __restrict__ C, int ldc, int K, int Nvalid) {
  const int orig = blockIdx.x + gridDim.x * blockIdx.y;
  const int xcd = orig & 7;
  const int cid = orig >> 3;
  const int rpx = gridDim.y >> 3;  // rows per XCD
  const int tn = cid / rpx;
  const int tm = xcd * rpx + (cid % rpx);
  __shared__ __align__(16) short As[128 * 32];
  __shared__ __align__(16) short Bs[128 * 32];
  const int t = threadIdx.x;
  const int w = t >> 6, lane = t & 63;
  const int m0 = tm * 128, n0 = tn * 128;
  const int wr = (w >> 1) * 64, wc = (w & 1) * 64;
  const int arow = t >> 2, kk = (t & 3) * 8;
  const int fr = lane & 15, fk = (lane >> 4) * 8;
  int br0 = n0 + arow;       if (br0 > Nvalid - 1) br0 = Nvalid - 1;
  int br1 = n0 + 64 + arow;  if (br1 > Nvalid - 1) br1 = Nvalid - 1;
  const short* pa0 = A + (size_t)(m0 + arow) * lda + kk;
  const short* pa1 = A + (size_t)(m0 + 64 + arow) * lda + kk;
  const short* pb0 = B + (size_t)br0 * ldb + kk;
  const short* pb1 = B + (size_t)br1 * ldb + kk;
  short* la = As + w * 512;
  short* lb = Bs + w * 512;
  f32x4 acc[4][4];
#pragma unroll
  for (int i = 0; i < 4; ++i)
#pragma unroll
    for (int j = 0; j < 4; ++j) acc[i][j] = (f32x4){0.f, 0.f, 0.f, 0.f};

  for (int k0 = 0; k0 < K; k0 += 32) {
    gload16(pa0 + k0, la);
    gload16(pa1 + k0, la + 2048);
    gload16(pb0 + k0, lb);
    gload16(pb1 + k0, lb + 2048);
    __syncthreads();
    short8 af[4], bg[4];
#pragma unroll
    for (int i = 0; i < 4; ++i) {
      af[i] = *(const short8*)&As[(wr + i * 16 + fr) * 32 + fk];
      bg[i] = *(const short8*)&Bs[(wc + i * 16 + fr) * 32 + fk];
    }
#pragma unroll
    for (int i = 0; i < 4; ++i)
#pragma unroll
      for (int j = 0; j < 4; ++j)
        acc[i][j] = __builtin_amdgcn_mfma_f32_16x16x32_bf16(af[i], bg[j],
                                                            acc[i][j], 0, 0, 0);
    __syncthreads();
  }
#pragma unroll
  for (int i = 0; i < 4; ++i) {
    const int row = m0 + wr + i * 16 + (lane >> 4) * 4;
#pragma unroll
    for (int j = 0; j < 4; ++j) {
      const int col = n0 + wc + j * 16 + fr;
      if (col < Nvalid) {
#pragma unroll
        for (int r = 0; r < 4; ++r)
          C[(size_t)(row + r) * ldc + col] = acc[i][j][r];
      }
    }
  }
}

// ---------------- conv halo save (before in-place conv) ----------------------
__global__ __launch_bounds__(256) void halo_kernel(const float* __restrict__ zx,
                                                   float* __restrict__ halo) {
  int idx = blockIdx.x * 256 + threadIdx.x;
  int ch = idx % 4224;
  int r = idx / 4224;
  int j = r % 3;
  int r2 = r / 3;
  int lc = r2 & 15, b = r2 >> 4;
  int l = lc * 128 - 3 + j;
  halo[idx] = (l < 0) ? 0.f : zx[(size_t)(b * 2048 + l) * DPROJ + 4096 + ch];
}

// ---------------- causal conv1d(4) + silu, in place on xBC slice -------------
__global__ __launch_bounds__(256) void conv_kernel(float* __restrict__ zx,
                                                   const float* __restrict__ halo,
                                                   const float* __restrict__ cw,
                                                   const float* __restrict__ cb) {
  int idx = blockIdx.x * 256 + threadIdx.x;
  int ch = idx % 4224;
  int r = idx / 4224;
  int lc = r & 15, b = r >> 4;
  float w0 = cw[ch * 4 + 0], w1 = cw[ch * 4 + 1], w2 = cw[ch * 4 + 2],
        w3 = cw[ch * 4 + 3];
  float bias = cb[ch];
  const float* hp = halo + (size_t)r * 3 * 4224 + ch;
  float x3 = hp[0], x2 = hp[4224], x1 = hp[2 * 4224];
  size_t base = (size_t)(b * 2048 + lc * 128) * DPROJ + 4096 + ch;
  for (int i = 0; i < 128; ++i) {
    float x0 = zx[base];
    float v = bias + w0 * x3 + w1 * x2 + w2 * x1 + w3 * x0;
    v = v / (1.f + __expf(-v));
    zx[base] = v;
    x3 = x2; x2 = x1; x1 = x0;
    base += DPROJ;
  }
}

// ---------------- dt softplus + per-chunk cumsum of dt*A ---------------------
__global__ __launch_bounds__(256) void dtacum_kernel(
    const float* __restrict__ zx, const float* __restrict__ dt_bias,
    const float* __restrict__ A_log, float* __restrict__ dtb,
    float* __restrict__ acu) {
  int bid = blockIdx.x;
  int c = bid & 7, h = (bid >> 3) & 63, b = bid >> 9;
  int s = threadIdx.x;
  int tok = b * 2048 + c * 256 + s;
  float raw = zx[(size_t)tok * DPROJ + 8320 + h] + dt_bias[h];
  float dtv = (raw > 20.f) ? raw : log1pf(expf(raw));
  float A = -expf(A_log[h]);
  __shared__ float sc[256];
  sc[s] = dtv * A;
  __syncthreads();
  for (int off = 1; off < 256; off <<= 1) {
    float v = (s >= off) ? sc[s - off] : 0.f;
    __syncthreads();
    sc[s] += v;
    __syncthreads();
  }
  int o = (b * 64 + h) * 2048 + c * 256 + s;
  dtb[o] = dtv;
  acu[o] = sc[s];
}

// ---------------- CB^T per (b,c), TRANSPOSED bf16: cbtT[l][s] ----------------
__global__ __launch_bounds__(256) void cbt_kernel(const float* __restrict__ zx,
                                                  short* __restrict__ cbtT) {
  __shared__ float cl[256][33];
  __shared__ float blds[16][32];
  int bid = blockIdx.x;
  int sb = bid & 15, c = (bid >> 4) & 7, b = bid >> 7;
  int t = threadIdx.x;  // = l
  int tok0 = b * 2048 + c * 256;
  float acc[16];
#pragma unroll
  for (int i = 0; i < 16; ++i) acc[i] = 0.f;
  for (int nh = 0; nh < 2; ++nh) {
    __syncthreads();
    for (int it = 0; it < 32; ++it) {
      int e = it * 256 + t;
      int row = e >> 5, n = e & 31;
      cl[row][n] = zx[(size_t)(tok0 + row) * DPROJ + 8256 + nh * 32 + n];
    }
    for (int it = 0; it < 2; ++it) {
      int e = it * 256 + t;
      int row = e >> 5, n = e & 31;
      blds[row][n] =
          zx[(size_t)(tok0 + sb * 16 + row) * DPROJ + 8192 + nh * 32 + n];
    }
    __syncthreads();
    for (int n = 0; n < 32; ++n) {
      float cv = cl[t][n];
#pragma unroll
      for (int s2 = 0; s2 < 16; ++s2) acc[s2] += cv * blds[s2][n];
    }
  }
  short* outp = cbtT + ((size_t)(b * 8 + c) * 256 + t) * 256 + sb * 16;
#pragma unroll
  for (int s2 = 0; s2 < 16; ++s2) outp[s2] = f2bf(acc[s2]);
}

// ---------------- states (MFMA): st[p][n] = sum_s x[s,p] B[s,n] w[s] ---------
__global__ __launch_bounds__(256) void states_mfma(
    const float* __restrict__ zx, const float* __restrict__ dtb,
    const float* __restrict__ acu, float* __restrict__ st) {
  __shared__ __align__(16) short As2[64][136];  // X^T [p][k]
  __shared__ __align__(16) short Bs2[64][136];  // (B·w)^T [n][k]
  __shared__ float wl[256];
  int bid = blockIdx.x;  // (b*8+c)*64 + h
  int h = bid & 63, c = (bid >> 6) & 7, b = bid >> 9;
  int t = threadIdx.x;
  int w = t >> 6, lane = t & 63;
  int tok0 = b * 2048 + c * 256;
  int bh = (b * 64 + h) * 2048 + c * 256;
  {
    float aend = acu[bh + 255];
    wl[t] = __expf(aend - acu[bh + t]) * dtb[bh + t];
  }
  __syncthreads();
  const float* xbase = zx + (size_t)tok0 * DPROJ + 4096 + h * 64;
  const float* bbase = zx + (size_t)tok0 * DPROJ + 8192;
  const int fr = lane & 15, fko = (lane >> 4) * 8;
  const int wi = (w >> 1) * 32, wj = (w & 1) * 32;
  f32x4 acc[2][2];
#pragma unroll
  for (int i = 0; i < 2; ++i)
#pragma unroll
    for (int j = 0; j < 2; ++j) acc[i][j] = (f32x4){0.f, 0.f, 0.f, 0.f};

  for (int ph = 0; ph < 2; ++ph) {
    const int kb = ph * 128;
    if (ph) __syncthreads();
    for (int it = 0; it < 8; ++it) {
      int idx = it * 256 + t;
      int p = idx & 63, kg = idx >> 6;  // kg 0..31
      int k = kb + kg * 4;
      const float* xp = xbase + (size_t)k * DPROJ + p;
      const float* bp = bbase + (size_t)k * DPROJ + p;
      sh4 oa, ob;
#pragma unroll
      for (int r = 0; r < 4; ++r) {
        oa[r] = f2bf(xp[(size_t)r * DPROJ]);
        ob[r] = f2bf(bp[(size_t)r * DPROJ] * wl[k + r]);
      }
      *(sh4*)&As2[p][kg * 4] = oa;
      *(sh4*)&Bs2[p][kg * 4] = ob;
    }
    __syncthreads();
#pragma unroll
    for (int kk0 = 0; kk0 < 128; kk0 += 32) {
      short8 af[2], bg[2];
#pragma unroll
      for (int i = 0; i < 2; ++i) {
        af[i] = *(const short8*)&As2[wi + i * 16 + fr][kk0 + fko];
        bg[i] = *(const short8*)&Bs2[wj + i * 16 + fr][kk0 + fko];
      }
#pragma unroll
      for (int i = 0; i < 2; ++i)
#pragma unroll
        for (int j = 0; j < 2; ++j)
          acc[i][j] = __builtin_amdgcn_mfma_f32_16x16x32_bf16(af[i], bg[j],
                                                              acc[i][j], 0, 0, 0);
    }
  }
  float* out = st + ((size_t)(b * 8 + c) * 64 + h) * 4096;
  const int rq = (lane >> 4) * 4;
#pragma unroll
  for (int i = 0; i < 2; ++i) {
    int p0 = wi + i * 16 + rq;
#pragma unroll
    for (int j = 0; j < 2; ++j) {
      int n = wj + j * 16 + fr;
#pragma unroll
      for (int r = 0; r < 4; ++r)
        out[(size_t)(p0 + r) * 64 + n] = acc[i][j][r];
    }
  }
}

// ---------------- inter-chunk scan (in place states -> prev_states) ---------
__global__ __launch_bounds__(256) void chunkscan_kernel(
    const float* __restrict__ acu, float* __restrict__ st) {
  int bid = blockIdx.x;
  int pc = bid & 15, h = (bid >> 4) & 63, b = bid >> 10;
  int pn = pc * 256 + threadIdx.x;
  int abase = (b * 64 + h) * 2048;
  float run = 0.f;
  for (int c = 0; c < 8; ++c) {
    size_t idx = ((size_t)(b * 8 + c) * 64 + h) * 4096 + pn;
    float s = st[idx];
    st[idx] = run;
    float ach = acu[abase + c * 256 + 255];
    run = run * __expf(ach) + s;
  }
}

// ---------------- Y (MFMA): M=256 l, N=64 p, K=320 (256 s + 64 n) ------------
__global__ __launch_bounds__(256) void ydiag_mfma(
    const float* __restrict__ zx, const float* __restrict__ dtb,
    const float* __restrict__ acu, const short* __restrict__ cbtT,
    const float* __restrict__ st, const float* __restrict__ Dp,
    float* __restrict__ yb) {
  __shared__ __align__(16) short Xs[64][328];  // [p][k]: k<256 x, k>=256 prev
  __shared__ float acs[256];
  __shared__ float dts[256];
  int bid = blockIdx.x;  // (b*8+c)*64 + h
  int h = bid & 63, c = (bid >> 6) & 7, b = bid >> 9;
  int t = threadIdx.x;
  int w = t >> 6, lane = t & 63;
  int tok0 = b * 2048 + c * 256;
  int bh = (b * 64 + h) * 2048 + c * 256;
  acs[t] = acu[bh + t];
  dts[t] = dtb[bh + t];
  const float* xbase = zx + (size_t)tok0 * DPROJ + 4096 + h * 64;
  const float* st_b = st + ((size_t)(b * 8 + c) * 64 + h) * 4096;
  for (int it = 0; it < 16; ++it) {
    int idx = it * 256 + t;
    int p = idx & 63, kg = idx >> 6;  // kg 0..63
    const float* xp = xbase + (size_t)(kg * 4) * DPROJ + p;
    sh4 o;
    o[0] = f2bf(xp[0]);
    o[1] = f2bf(xp[DPROJ]);
    o[2] = f2bf(xp[2 * DPROJ]);
    o[3] = f2bf(xp[3 * DPROJ]);
    *(sh4*)&Xs[p][kg * 4] = o;
  }
  for (int it = 0; it < 4; ++it) {
    int idx = it * 256 + t;
    int ng = idx & 15, p = idx >> 4;
    float4 v = *(const float4*)&st_b[p * 64 + ng * 4];
    sh4 o;
    o[0] = f2bf(v.x); o[1] = f2bf(v.y); o[2] = f2bf(v.z); o[3] = f2bf(v.w);
    *(sh4*)&Xs[p][256 + ng * 4] = o;
  }
  __syncthreads();

  const int fr = lane & 15, fko = (lane >> 4) * 8;
  const int wr = w * 64;
  float Al[4], eAl[4];
#pragma unroll
  for (int i = 0; i < 4; ++i) {
    Al[i] = acs[wr + i * 16 + fr];
    eAl[i] = __expf(Al[i]);
  }
  f32x4 acc[4][4];
#pragma unroll
  for (int i = 0; i < 4; ++i)
#pragma unroll
    for (int j = 0; j < 4; ++j) acc[i][j] = (f32x4){0.f, 0.f, 0.f, 0.f};

  const short* cbt_b = cbtT + (size_t)(b * 8 + c) * 65536;

  // masked decay part: s in [0, wr+64)
  for (int k0 = 0; k0 < wr + 64; k0 += 32) {
    short8 bg[4];
#pragma unroll
    for (int j = 0; j < 4; ++j)
      bg[j] = *(const short8*)&Xs[j * 16 + fr][k0 + fko];
    const int bi = (k0 + 32 < 256) ? (k0 + 32) : 255;
    const float base = acs[bi];
    float vd[8];
#pragma unroll
    for (int jj = 0; jj < 8; ++jj) {
      int s = k0 + fko + jj;
      vd[jj] = __expf(base - acs[s]) * dts[s];
    }
#pragma unroll
    for (int i = 0; i < 4; ++i) {
      const int li0 = wr + i * 16;
      if (k0 > li0 + 15) continue;  // fragment fully above diagonal: zero
      const int l = li0 + fr;
      const short8 cb = *(const short8*)&cbt_b[(size_t)l * 256 + k0 + fko];
      short8 af;
      if (k0 + 32 <= li0) {
        const float u = __expf(Al[i] - base);
#pragma unroll
        for (int jj = 0; jj < 8; ++jj)
          af[jj] = f2bf(bf2f(cb[jj]) * (vd[jj] * u));
      } else {
#pragma unroll
        for (int jj = 0; jj < 8; ++jj) {
          int s = k0 + fko + jj;
          float wv = 0.f;
          if (s <= l) wv = bf2f(cb[jj]) * __expf(Al[i] - acs[s]) * dts[s];
          af[jj] = f2bf(wv);
        }
      }
#pragma unroll
      for (int j = 0; j < 4; ++j)
        acc[i][j] = __builtin_amdgcn_mfma_f32_16x16x32_bf16(af, bg[j],
                                                            acc[i][j], 0, 0, 0);
    }
  }
  // Y_off part: k in [256, 320) -> n = k-256; C read straight from zx
#pragma unroll
  for (int k0 = 256; k0 < 320; k0 += 32) {
    short8 bg[4];
#pragma unroll
    for (int j = 0; j < 4; ++j)
      bg[j] = *(const short8*)&Xs[j * 16 + fr][k0 + fko];
#pragma unroll
    for (int i = 0; i < 4; ++i) {
      const int l = wr + i * 16 + fr;
      const float* cr =
          zx + (size_t)(tok0 + l) * DPROJ + 8256 + (k0 - 256) + fko;
      float4 c0 = *(const float4*)cr;
      float4 c1 = *(const float4*)(cr + 4);
      short8 af;
      af[0] = f2bf(c0.x * eAl[i]); af[1] = f2bf(c0.y * eAl[i]);
      af[2] = f2bf(c0.z * eAl[i]); af[3] = f2bf(c0.w * eAl[i]);
      af[4] = f2bf(c1.x * eAl[i]); af[5] = f2bf(c1.y * eAl[i]);
      af[6] = f2bf(c1.z * eAl[i]); af[7] = f2bf(c1.w * eAl[i]);
#pragma unroll
      for (int j = 0; j < 4; ++j)
        acc[i][j] = __builtin_amdgcn_mfma_f32_16x16x32_bf16(af, bg[j],
                                                            acc[i][j], 0, 0, 0);
    }
  }
  // epilogue: + D*x, store
  float Dh = Dp[h];
  const int rq = (lane >> 4) * 4;
#pragma unroll
  for (int i = 0; i < 4; ++i) {
    int l0 = wr + i * 16 + rq;
#pragma unroll
    for (int j = 0; j < 4; ++j) {
      int p = j * 16 + fr;
      sh4 x4 = *(const sh4*)&Xs[p][l0];
      f32x4 a = acc[i][j];
#pragma unroll
      for (int r = 0; r < 4; ++r)
        yb[(size_t)(bh + l0 + r) * 64 + p] = a[r] + Dh * bf2f(x4[r]);
    }
  }
}

// ---------------- gate + RMSNorm -> bf16 activations (aliases zx z-slice) ----
__global__ __launch_bounds__(256) void gatenorm_kernel(
    const float* zx, const float* __restrict__ nw,
    const float* __restrict__ yb, short* ybh) {
  int tok = blockIdx.x;
  int b = tok >> 11, l = tok & 2047;
  int t = threadIdx.x;
  float g[16];
  float ss = 0.f;
#pragma unroll
  for (int i = 0; i < 16; ++i) {
    int d = i * 256 + t;
    int h = d >> 6, p = d & 63;
    float yv = yb[((size_t)(b * 64 + h) * 2048 + l) * 64 + p];
    float zv = zx[(size_t)tok * DPROJ + d];
    float gv = yv * (zv / (1.f + __expf(-zv)));
    g[i] = gv;
    ss += gv * gv;
  }
  for (int off = 32; off > 0; off >>= 1) ss += __shfl_down(ss, off);
  __shared__ float red[4];
  int wid = t >> 6, lane = t & 63;
  if (lane == 0) red[wid] = ss;
  __syncthreads();
  float tot = red[0] + red[1] + red[2] + red[3];
  float scale = rsqrtf(tot * (1.f / 4096.f) + 1e-5f);
#pragma unroll
  for (int i = 0; i < 16; ++i) {
    int d = i * 256 + t;
    ybh[(size_t)tok * 16768 + d] = f2bf(g[i] * scale * nw[d]);
  }
}

extern "C" void kernel_launch(void* const* d_in, const int* in_sizes, int n_in,
                              void* d_out, int out_size, void* d_ws,
                              size_t ws_size, hipStream_t stream) {
  const float* u = (const float*)d_in[0];
  const float* W_in = (const float*)d_in[1];
  const float* conv_w = (const float*)d_in[2];
  const float* conv_b = (const float*)d_in[3];
  const float* dt_bias = (const float*)d_in[4];
  const float* A_log = (const float*)d_in[5];
  const float* Dp = (const float*)d_in[6];
  const float* norm_w = (const float*)d_in[7];
  const float* W_out = (const float*)d_in[8];
  float* out = (float*)d_out;
  float* ws = (float*)d_ws;

  float* zx = ws + ZX_OFF;
  float* dtb = ws + DTB_OFF;
  float* acu = ws + ACU_OFF;
  short* cbtT = (short*)(ws + CBT_OFF);
  float* st = ws + ST_OFF;
  float* yb = ws + YB_OFF;
  float* halo = ws + HALO_OFF;
  short* u16 = (short*)(ws + U16_OFF);
  short* win16 = (short*)(ws + WIN16_OFF);
  short* wout16 = (short*)(ws + WOUT16_OFF);
  short* ybh = (short*)zx;

  // 0. casts for in_proj
  cast_bf16_kernel<<<4096, 256, 0, stream>>>(u, u16, 1048576);
  cast_bf16_kernel<<<8384, 256, 0, stream>>>(W_in, win16, 2146304);
  // 1. in_proj (256^2 full-tile-prefetch MFMA): zx = u @ W_in^T
  gemm_8ph<<<dim3(33, 16), 512, 0, stream>>>(u16, 2048, win16, 2048, zx, DPROJ,
                                             2048, DPROJ);
  // 2. conv halo, in-place conv+silu
  halo_kernel<<<1584, 256, 0, stream>>>(zx, halo);
  conv_kernel<<<528, 256, 0, stream>>>(zx, halo, conv_w, conv_b);
  // 3. dt softplus + per-chunk cumsum (reads zx dt slice)
  dtacum_kernel<<<1024, 256, 0, stream>>>(zx, dt_bias, A_log, dtb, acu);
  // 4. shared C·B^T (transposed bf16)
  cbt_kernel<<<256, 256, 0, stream>>>(zx, cbtT);
  // 5. chunk states (MFMA) + inter-chunk scan
  states_mfma<<<1024, 256, 0, stream>>>(zx, dtb, acu, st);
  chunkscan_kernel<<<2048, 256, 0, stream>>>(acu, st);
  // 6. Y (MFMA)
  ydiag_mfma<<<1024, 256, 0, stream>>>(zx, dtb, acu, cbtT, st, Dp, yb);
  // 7. W_out cast
  cast_bf16_kernel<<<4096, 256, 0, stream>>>(W_out, wout16, 1048576);
  // 8. gate + RMSNorm -> bf16
  gatenorm_kernel<<<4096, 256, 0, stream>>>(zx, norm_w, yb, ybh);
  // 9. out_proj (bf16 MFMA, m97 structure)
  gemm_bf16<<<dim3(16, 32), 256, 0, stream>>>(ybh, 16768, wout16, 4096, out,
                                              2048, 4096, 2048);
}